// Round 1
// baseline (10.049 us; speedup 1.0000x reference)
//
#include <hip/hip_runtime.h>

// Forward value of straight-through estimator:
//   out = stop_gradient(ones - y) + y  ==  ones   (numerically)
// The entire segment-softmax pipeline affects only gradients, which are not
// part of this problem's output. So the kernel is a pure fill of 1.0f.

__global__ void Sampler_fill_ones(float4* __restrict__ out4, int n4,
                                  float* __restrict__ out_tail, int tail_start, int n) {
    int i = blockIdx.x * blockDim.x + threadIdx.x;
    if (i < n4) {
        out4[i] = make_float4(1.0f, 1.0f, 1.0f, 1.0f);
    }
    // tail (n not divisible by 4): first few threads handle it
    int t = tail_start + i;
    if (i < 4 && t < n) {
        out_tail[t] = 1.0f;
    }
}

extern "C" void kernel_launch(void* const* d_in, const int* in_sizes, int n_in,
                              void* d_out, int out_size, void* d_ws, size_t ws_size,
                              hipStream_t stream) {
    (void)d_in; (void)in_sizes; (void)n_in; (void)d_ws; (void)ws_size;
    float* out = (float*)d_out;
    int n  = out_size;          // 512000
    int n4 = n >> 2;            // 128000 float4 stores
    int tail_start = n4 << 2;
    int block = 256;
    int grid = (n4 + block - 1) / block;   // 500 blocks
    if (grid < 1) grid = 1;
    Sampler_fill_ones<<<grid, block, 0, stream>>>(
        (float4*)out, n4, out, tail_start, n);
}